// Round 1
// baseline (412.394 us; speedup 1.0000x reference)
//
#include <hip/hip_runtime.h>
#include <hip/hip_bf16.h>

#define NB   32
#define CIN  128
#define HH   56
#define WW   56
#define COUT 256
#define HW   3136   // 56*56

typedef __bf16 bf16x8 __attribute__((ext_vector_type(8)));
typedef float floatx4 __attribute__((ext_vector_type(4)));

// ---------------- 1) global average pool: gap[b][c] ----------------
__global__ void gap_kernel(const float* __restrict__ x, float* __restrict__ gap) {
    int bc = blockIdx.x;  // b*128 + c
    const float4* p = (const float4*)(x + (size_t)bc * HW);
    float s = 0.f;
    for (int j = threadIdx.x; j < HW / 4; j += 256) {
        float4 v = p[j];
        s += v.x + v.y + v.z + v.w;
    }
    #pragma unroll
    for (int off = 32; off > 0; off >>= 1) s += __shfl_down(s, off, 64);
    __shared__ float red[4];
    if ((threadIdx.x & 63) == 0) red[threadIdx.x >> 6] = s;
    __syncthreads();
    if (threadIdx.x == 0)
        gap[bc] = (red[0] + red[1] + red[2] + red[3]) * (1.0f / HW);
}

// ---------------- 2) router MLP + softmax(logits/30) ----------------
__global__ void router_kernel(const float* __restrict__ gap,
                              const float* __restrict__ w1, const float* __restrict__ b1,
                              const float* __restrict__ w2, const float* __restrict__ b2,
                              float* __restrict__ routing) {
    int b = threadIdx.x;
    if (b >= NB) return;
    float h[16];
    #pragma unroll
    for (int r = 0; r < 16; ++r) {
        float s = b1[r];
        for (int i = 0; i < CIN; ++i) s += gap[b * CIN + i] * w1[r * CIN + i];
        h[r] = fmaxf(s, 0.f);
    }
    float lg[4]; float mx = -1e30f;
    #pragma unroll
    for (int e = 0; e < 4; ++e) {
        float s = b2[e];
        #pragma unroll
        for (int r = 0; r < 16; ++r) s += h[r] * w2[e * 16 + r];
        lg[e] = s * (1.0f / 30.0f);
        mx = fmaxf(mx, lg[e]);
    }
    float den = 0.f, ex[4];
    #pragma unroll
    for (int e = 0; e < 4; ++e) { ex[e] = expf(lg[e] - mx); den += ex[e]; }
    #pragma unroll
    for (int e = 0; e < 4; ++e) routing[b * 4 + e] = ex[e] / den;
}

// ---------------- 3) mix expert kernels -> bf16, layout [b][p][o][i] ----------------
__global__ void mix_kernel(const float* __restrict__ convs,
                           const float* __restrict__ routing,
                           __hip_bfloat16* __restrict__ wmix) {
    int idx = blockIdx.x * 256 + threadIdx.x;       // ((b*9+p)*256+o)*128+i
    int i = idx & 127;
    int o = (idx >> 7) & 255;
    int t = idx >> 15;                              // b*9 + p  (256*128 = 2^15)
    int p = t % 9;
    int b = t / 9;
    const float* r = routing + b * 4;
    int base = (o * CIN + i) * 9 + p;               // convs[e][o][i][ky][kx]
    const int ES = COUT * CIN * 9;                  // 294912
    float s = r[0] * convs[base] + r[1] * convs[base + ES]
            + r[2] * convs[base + 2 * ES] + r[3] * convs[base + 3 * ES];
    wmix[idx] = __float2bfloat16(s);
}

// ---------------- 4) x: NCHW fp32 -> NHWC bf16  [b][y][x][i] ----------------
__global__ void xpose_kernel(const float* __restrict__ x, __hip_bfloat16* __restrict__ xT) {
    // grid (49, 2, 32): 64-wide hw tile, 64-wide i tile
    int hw0 = blockIdx.x * 64, i0 = blockIdx.y * 64, b = blockIdx.z;
    __shared__ float tile[64][65];
    const float* xp = x + ((size_t)b * CIN + i0) * HW + hw0;
    for (int t = threadIdx.x; t < 4096; t += 256) {
        int ir = t >> 6, c = t & 63;
        tile[ir][c] = xp[(size_t)ir * HW + c];
    }
    __syncthreads();
    __hip_bfloat16* op = xT + (size_t)b * HW * CIN + (size_t)hw0 * CIN + i0;
    for (int t = threadIdx.x; t < 4096; t += 256) {
        int pp = t >> 6, ii = t & 63;
        op[(size_t)pp * CIN + ii] = __float2bfloat16(tile[ii][pp]);
    }
}

// ---------------- 5) dynamic conv as 9 shifted MFMA GEMMs ----------------
// block: M=128 (Cout half) x N=128 spatial (8 rows x 16 cols), 4 waves, 4x4 16x16 acc/wave
// K-loop: cc in {0,1} (Cin chunk of 64) x 9 taps x 2 MFMA k-steps (K=32)
__global__ __launch_bounds__(256, 2)
void conv_mfma(const __hip_bfloat16* __restrict__ xT,
               const __hip_bfloat16* __restrict__ wmix,
               float* __restrict__ out) {
    __shared__ __align__(16) __hip_bfloat16 xs[180 * 72];   // (8+2)*(16+2) px, 64ch, pad->72
    __shared__ __align__(16) __hip_bfloat16 wls[128 * 72];  // 128 o, 64ch, pad->72

    const int tile = blockIdx.x;          // 0..27 = yt*4 + xt
    const int yt = tile >> 2, xt = tile & 3;
    const int mtile = blockIdx.y;         // 0..1
    const int b = blockIdx.z;             // 0..31
    const int y0 = yt * 8, x0 = xt * 16;
    const int tid = threadIdx.x;
    const int lane = tid & 63, wave = tid >> 6;
    const int wm = wave & 1, wn = wave >> 1;
    const int col = lane & 15, quad = lane >> 4;

    floatx4 acc[4][4];
    #pragma unroll
    for (int mt = 0; mt < 4; ++mt)
        #pragma unroll
        for (int nt = 0; nt < 4; ++nt)
            acc[mt][nt] = (floatx4){0.f, 0.f, 0.f, 0.f};

    const __hip_bfloat16* xb = xT + (size_t)b * HW * CIN;

    for (int cc = 0; cc < 2; ++cc) {
        __syncthreads();  // previous iter's reads of xs/wls complete
        // stage x halo tile chunk: 180 px * 8 segs of 8 bf16
        for (int t = tid; t < 180 * 8; t += 256) {
            int pix = t >> 3, seg = t & 7;
            int py = pix / 18, px = pix - py * 18;
            int gy = y0 - 1 + py, gx = x0 - 1 + px;
            uint4 v = {0u, 0u, 0u, 0u};
            if ((unsigned)gy < 56u && (unsigned)gx < 56u)
                v = *(const uint4*)(xb + ((size_t)(gy * 56 + gx) * CIN + cc * 64 + seg * 8));
            *(uint4*)(&xs[pix * 72 + seg * 8]) = v;
        }
        for (int p = 0; p < 9; ++p) {
            const int ky = p / 3, kx = p - ky * 3;
            if (p) __syncthreads();  // previous tap's compute done before wls overwrite
            for (int t = tid; t < 128 * 8; t += 256) {
                int m = t >> 3, seg = t & 7;
                uint4 v = *(const uint4*)(wmix +
                    ((((size_t)b * 9 + p) * COUT + mtile * 128 + m) * CIN + cc * 64 + seg * 8));
                *(uint4*)(&wls[m * 72 + seg * 8]) = v;
            }
            __syncthreads();
            #pragma unroll
            for (int ks = 0; ks < 2; ++ks) {
                const int i0 = ks * 32 + quad * 8;
                bf16x8 af[4], bfr[4];
                #pragma unroll
                for (int mt = 0; mt < 4; ++mt)
                    af[mt] = *(const bf16x8*)(&wls[(wm * 64 + mt * 16 + col) * 72 + i0]);
                #pragma unroll
                for (int nt = 0; nt < 4; ++nt) {
                    int pyy = wn * 4 + nt + ky;   // ty + ky (LDS row 0 = y0-1)
                    int pxx = col + kx;           // tx + kx
                    bfr[nt] = *(const bf16x8*)(&xs[(pyy * 18 + pxx) * 72 + i0]);
                }
                #pragma unroll
                for (int mt = 0; mt < 4; ++mt)
                    #pragma unroll
                    for (int nt = 0; nt < 4; ++nt)
                        acc[mt][nt] = __builtin_amdgcn_mfma_f32_16x16x32_bf16(
                            af[mt], bfr[nt], acc[mt][nt], 0, 0, 0);
            }
        }
    }

    // epilogue: C/D layout col=lane&15, row=quad*4+reg
    const int x = x0 + col;
    if (x < 56) {
        #pragma unroll
        for (int mt = 0; mt < 4; ++mt) {
            int o = mtile * 128 + wm * 64 + mt * 16 + quad * 4;
            #pragma unroll
            for (int nt = 0; nt < 4; ++nt) {
                int y = y0 + wn * 4 + nt;
                float* op = out + (((size_t)b * COUT + o) * 56 + y) * 56 + x;
                #pragma unroll
                for (int r = 0; r < 4; ++r)
                    op[(size_t)r * HW] = acc[mt][nt][r];
            }
        }
    }
}

extern "C" void kernel_launch(void* const* d_in, const int* in_sizes, int n_in,
                              void* d_out, int out_size, void* d_ws, size_t ws_size,
                              hipStream_t stream) {
    const float* x     = (const float*)d_in[0];
    const float* convs = (const float*)d_in[1];
    const float* w1    = (const float*)d_in[2];
    const float* b1    = (const float*)d_in[3];
    const float* w2    = (const float*)d_in[4];
    const float* b2    = (const float*)d_in[5];
    float* out = (float*)d_out;

    char* ws = (char*)d_ws;
    // workspace layout (44.6 MB total)
    float* gap              = (float*)ws;                         // 32*128*4       = 16384 B
    float* routing          = (float*)(ws + 16384);               // 32*4*4         = 512 B
    __hip_bfloat16* xT      = (__hip_bfloat16*)(ws + 16896);      // 32*3136*128*2  = 25690112 B
    __hip_bfloat16* wmix    = (__hip_bfloat16*)(ws + 16896 + 25690112); // 32*9*256*128*2 = 18874368 B

    gap_kernel   <<<NB * CIN, 256, 0, stream>>>(x, gap);
    router_kernel<<<1, 64, 0, stream>>>(gap, w1, b1, w2, b2, routing);
    mix_kernel   <<<(NB * 9 * COUT * CIN) / 256, 256, 0, stream>>>(convs, routing, wmix);
    xpose_kernel <<<dim3(49, 2, NB), 256, 0, stream>>>(x, xT);
    conv_mfma    <<<dim3(28, 2, NB), 256, 0, stream>>>(xT, wmix, out);
}

// Round 2
// 404.600 us; speedup vs baseline: 1.0193x; 1.0193x over previous
//
#include <hip/hip_runtime.h>
#include <hip/hip_bf16.h>

#define NB   32
#define CIN  128
#define HH   56
#define WW   56
#define COUT 256
#define HW   3136   // 56*56

typedef __bf16 bf16x8 __attribute__((ext_vector_type(8)));
typedef float floatx4 __attribute__((ext_vector_type(4)));

// ---------------- 1) router MLP + softmax(logits/30); gap is pre-summed (needs *1/HW) ----------------
__global__ void router_kernel(const float* __restrict__ gap,
                              const float* __restrict__ w1, const float* __restrict__ b1,
                              const float* __restrict__ w2, const float* __restrict__ b2,
                              float* __restrict__ routing) {
    int b = threadIdx.x;
    if (b >= NB) return;
    const float inv = 1.0f / HW;
    float h[16];
    #pragma unroll
    for (int r = 0; r < 16; ++r) {
        float s = 0.f;
        for (int i = 0; i < CIN; ++i) s += gap[b * CIN + i] * w1[r * CIN + i];
        h[r] = fmaxf(fmaf(s, inv, b1[r]), 0.f);
    }
    float lg[4]; float mx = -1e30f;
    #pragma unroll
    for (int e = 0; e < 4; ++e) {
        float s = b2[e];
        #pragma unroll
        for (int r = 0; r < 16; ++r) s += h[r] * w2[e * 16 + r];
        lg[e] = s * (1.0f / 30.0f);
        mx = fmaxf(mx, lg[e]);
    }
    float den = 0.f, ex[4];
    #pragma unroll
    for (int e = 0; e < 4; ++e) { ex[e] = expf(lg[e] - mx); den += ex[e]; }
    #pragma unroll
    for (int e = 0; e < 4; ++e) routing[b * 4 + e] = ex[e] / den;
}

// ---------------- 2) mix expert kernels -> bf16, layout [b][p][o][i] ----------------
// one thread per (b,o,i): all 9 taps. convs[e][o][i][p] reads are 9 consecutive floats.
__global__ void mix_kernel(const float* __restrict__ convs,
                           const float* __restrict__ routing,
                           __hip_bfloat16* __restrict__ wmix) {
    int idx = blockIdx.x * 256 + threadIdx.x;       // (b*COUT + o)*CIN + i
    int i = idx & 127;
    int o = (idx >> 7) & 255;
    int b = idx >> 15;
    const float* r = routing + b * 4;
    float r0 = r[0], r1 = r[1], r2 = r[2], r3 = r[3];
    const float* cb = convs + (size_t)(o * CIN + i) * 9;
    const int ES = COUT * CIN * 9;                  // 294912
    float s[9];
    #pragma unroll
    for (int p = 0; p < 9; ++p)
        s[p] = r0 * cb[p] + r1 * cb[p + ES] + r2 * cb[p + 2 * ES] + r3 * cb[p + 3 * ES];
    __hip_bfloat16* wp = wmix + ((size_t)b * 9 * COUT + o) * CIN + i;
    #pragma unroll
    for (int p = 0; p < 9; ++p)
        wp[(size_t)p * COUT * CIN] = __float2bfloat16(s[p]);
}

// ---------------- 3) x: NCHW fp32 -> NHWC bf16 [b][y][x][i], fused GAP partial sums ----------------
__global__ void xpose_kernel(const float* __restrict__ x, __hip_bfloat16* __restrict__ xT,
                             float* __restrict__ gap) {
    // grid (49, 2, 32): 64-wide hw tile, 64-wide i tile
    int hw0 = blockIdx.x * 64, i0 = blockIdx.y * 64, b = blockIdx.z;
    __shared__ float tile[64][65];
    const float* xp = x + ((size_t)b * CIN + i0) * HW + hw0;
    for (int t = threadIdx.x; t < 4096; t += 256) {
        int ir = t >> 6, c = t & 63;
        tile[ir][c] = xp[(size_t)ir * HW + c];
    }
    __syncthreads();
    // transposed bf16 writes, uint4 (8 ch) per store
    __hip_bfloat16* op = xT + ((size_t)b * HW + hw0) * CIN + i0;
    for (int t = threadIdx.x; t < 512; t += 256) {
        int pp = t >> 3, seg = t & 7;
        __hip_bfloat16 tmp[8];
        #pragma unroll
        for (int j = 0; j < 8; ++j) tmp[j] = __float2bfloat16(tile[seg * 8 + j][pp]);
        *(uint4*)(op + (size_t)pp * CIN + seg * 8) = *(uint4*)tmp;
    }
    // gap partials: 64 ch x 4 groups of 16 px
    int ch = threadIdx.x & 63, grp = threadIdx.x >> 6;
    float s = 0.f;
    #pragma unroll
    for (int k = 0; k < 16; ++k) s += tile[ch][grp * 16 + k];
    atomicAdd(gap + b * CIN + i0 + ch, s);
}

// ---------------- 4) dynamic conv: 9 shifted MFMA GEMMs, register-prefetch pipeline ----------------
__global__ __launch_bounds__(256, 3)
void conv_mfma(const __hip_bfloat16* __restrict__ xT,
               const __hip_bfloat16* __restrict__ wmix,
               float* __restrict__ out) {
    __shared__ __align__(16) __hip_bfloat16 xs[180 * 72];   // 10x18 px halo, 64ch, pad->72
    __shared__ __align__(16) __hip_bfloat16 wls[128 * 72];  // 128 o, 64ch, pad->72

    const int tile = blockIdx.x;          // 0..27 = yt*4 + xt
    const int yt = tile >> 2, xt = tile & 3;
    const int mtile = blockIdx.y;         // 0..1
    const int b = blockIdx.z;             // 0..31
    const int y0 = yt * 8, x0 = xt * 16;
    const int tid = threadIdx.x;
    const int lane = tid & 63, wave = tid >> 6;
    const int wm = wave & 1, wn = wave >> 1;
    const int col = lane & 15, quad = lane >> 4;

    floatx4 acc[4][4];
    #pragma unroll
    for (int mt = 0; mt < 4; ++mt)
        #pragma unroll
        for (int nt = 0; nt < 4; ++nt)
            acc[mt][nt] = (floatx4){0.f, 0.f, 0.f, 0.f};

    const __hip_bfloat16* xb = xT + (size_t)b * HW * CIN;
    const __hip_bfloat16* wb = wmix + (size_t)b * 9 * COUT * CIN + (size_t)mtile * 128 * CIN;

    uint4 xreg[6], wreg[4];

    // --- prefetch helpers (straight-line, compiler keeps loads in flight) ---
    #define LOADX(cc)                                                              \
        _Pragma("unroll")                                                          \
        for (int j = 0; j < 6; ++j) {                                              \
            int tt = tid + j * 256;                                                \
            uint4 v = {0u, 0u, 0u, 0u};                                            \
            if (tt < 1440) {                                                       \
                int pix = tt >> 3, seg = tt & 7;                                   \
                int py = pix / 18, px = pix - py * 18;                             \
                int gy = y0 - 1 + py, gx = x0 - 1 + px;                            \
                if ((unsigned)gy < 56u && (unsigned)gx < 56u)                      \
                    v = *(const uint4*)(xb + ((size_t)(gy * 56 + gx) * CIN +       \
                                              (cc) * 64 + seg * 8));               \
            }                                                                      \
            xreg[j] = v;                                                           \
        }
    #define STOREX()                                                               \
        _Pragma("unroll")                                                          \
        for (int j = 0; j < 6; ++j) {                                              \
            int tt = tid + j * 256;                                                \
            if (tt < 1440) {                                                       \
                int pix = tt >> 3, seg = tt & 7;                                   \
                *(uint4*)(&xs[pix * 72 + seg * 8]) = xreg[j];                      \
            }                                                                      \
        }
    #define LOADW(p, cc)                                                           \
        _Pragma("unroll")                                                          \
        for (int j = 0; j < 4; ++j) {                                              \
            int tt = tid + j * 256;                                                \
            int m = tt >> 3, seg = tt & 7;                                         \
            wreg[j] = *(const uint4*)(wb + ((size_t)(p) * COUT + m) * CIN +        \
                                      (cc) * 64 + seg * 8);                        \
        }
    #define STOREW()                                                               \
        _Pragma("unroll")                                                          \
        for (int j = 0; j < 4; ++j) {                                              \
            int tt = tid + j * 256;                                                \
            int m = tt >> 3, seg = tt & 7;                                         \
            *(uint4*)(&wls[m * 72 + seg * 8]) = wreg[j];                           \
        }

    LOADX(0);
    LOADW(0, 0);

    for (int cc = 0; cc < 2; ++cc) {
        STOREX();   // entry at cc=1 protected by trailing barrier of previous tap
        for (int p = 0; p < 9; ++p) {
            STOREW();
            // issue next prefetches (latency hidden by this tap's compute)
            if (p < 8)            { LOADW(p + 1, cc); }
            else if (cc == 0)     { LOADW(0, 1); }
            if (cc == 0 && p == 0) { LOADX(1); }
            __syncthreads();      // xs + wls visible to all waves

            const int ky = p / 3, kx = p - ky * 3;
            #pragma unroll
            for (int ks = 0; ks < 2; ++ks) {
                const int i0 = ks * 32 + quad * 8;
                bf16x8 af[4], bfr[4];
                #pragma unroll
                for (int mt = 0; mt < 4; ++mt)
                    af[mt] = *(const bf16x8*)(&wls[(wm * 64 + mt * 16 + col) * 72 + i0]);
                #pragma unroll
                for (int nt = 0; nt < 4; ++nt) {
                    int pyy = wn * 4 + nt + ky;   // LDS row 0 = y0-1
                    int pxx = col + kx;
                    bfr[nt] = *(const bf16x8*)(&xs[(pyy * 18 + pxx) * 72 + i0]);
                }
                #pragma unroll
                for (int mt = 0; mt < 4; ++mt)
                    #pragma unroll
                    for (int nt = 0; nt < 4; ++nt)
                        acc[mt][nt] = __builtin_amdgcn_mfma_f32_16x16x32_bf16(
                            af[mt], bfr[nt], acc[mt][nt], 0, 0, 0);
            }
            __syncthreads();      // compute done; next STOREW/STOREX may overwrite
        }
    }

    // epilogue: C/D layout col=lane&15, row=quad*4+reg
    const int x = x0 + col;
    if (x < 56) {
        #pragma unroll
        for (int mt = 0; mt < 4; ++mt) {
            int o = mtile * 128 + wm * 64 + mt * 16 + quad * 4;
            #pragma unroll
            for (int nt = 0; nt < 4; ++nt) {
                int y = y0 + wn * 4 + nt;
                float* op = out + (((size_t)b * COUT + o) * 56 + y) * 56 + x;
                #pragma unroll
                for (int r = 0; r < 4; ++r)
                    op[(size_t)r * HW] = acc[mt][nt][r];
            }
        }
    }
}

extern "C" void kernel_launch(void* const* d_in, const int* in_sizes, int n_in,
                              void* d_out, int out_size, void* d_ws, size_t ws_size,
                              hipStream_t stream) {
    const float* x     = (const float*)d_in[0];
    const float* convs = (const float*)d_in[1];
    const float* w1    = (const float*)d_in[2];
    const float* b1    = (const float*)d_in[3];
    const float* w2    = (const float*)d_in[4];
    const float* b2    = (const float*)d_in[5];
    float* out = (float*)d_out;

    char* ws = (char*)d_ws;
    float* gap              = (float*)ws;                               // 16384 B
    float* routing          = (float*)(ws + 16384);                     // 512 B
    __hip_bfloat16* xT      = (__hip_bfloat16*)(ws + 16896);            // 25690112 B
    __hip_bfloat16* wmix    = (__hip_bfloat16*)(ws + 16896 + 25690112); // 18874368 B

    hipMemsetAsync(gap, 0, NB * CIN * sizeof(float), stream);
    xpose_kernel <<<dim3(49, 2, NB), 256, 0, stream>>>(x, xT, gap);
    router_kernel<<<1, 64, 0, stream>>>(gap, w1, b1, w2, b2, routing);
    mix_kernel   <<<(NB * COUT * CIN) / 256, 256, 0, stream>>>(convs, routing, wmix);
    conv_mfma    <<<dim3(28, 2, NB), 256, 0, stream>>>(xT, wmix, out);
}